// Round 8
// baseline (190.491 us; speedup 1.0000x reference)
//
#include <hip/hip_runtime.h>
#include <math.h>

#define B_ 4
#define S_ 2048
#define D_ 128
#define EPSF 1e-5f
#define BN 128
#define PSB 272     // fallback-path Ps row stride
#define PRS 4128    // P_row stride bytes (2048*2 + 32): 16B-aligned, 8-bank row shift

typedef __attribute__((ext_vector_type(8))) short short8;
typedef __attribute__((ext_vector_type(4))) float f32x4;

static __device__ __forceinline__ unsigned short f2bf(float f) {
    unsigned u = __float_as_uint(f);
    return (unsigned short)((u + 0x7fffu + ((u >> 16) & 1u)) >> 16);
}

// ===================== pre-pass kernels =====================
// Qb/Kb: plain row-major bf16 [row][128]. Vtb: fragment-native per 128-key tile:
//   uint4 index = ks*512 + d*4 + quad  (keys (ks*4+quad)*8..+7 packed as 8 bf16 for dim d)
// ws bytes: [0,32K) qn, [32K,64K) kn, [64K,96K) lws, [96K,160K) qng, [160K,224K) kng,
//           [224K..) Qb(2M) Kb(2M) Vtb(2M)

__global__ __launch_bounds__(256) void convqk_kernel(const float* __restrict__ q,
                                                     const float* __restrict__ k,
                                                     const float* __restrict__ cp,
                                                     float* __restrict__ qn, float* __restrict__ kn,
                                                     float* __restrict__ lws,
                                                     float2* __restrict__ qng, float2* __restrict__ kng,
                                                     unsigned* __restrict__ Qb, unsigned* __restrict__ Kb) {
    int row = blockIdx.x * 4 + (threadIdx.x >> 6);   // one wave per row, 16384 rows
    int lane = threadIdx.x & 63;
    const int NR = B_ * S_;
    const float cc = cp[0];
    bool isQ = row < NR;
    int r = isQ ? row : row - NR;
    float2 v = ((const float2*)(isQ ? q : k))[(size_t)r * 64 + lane];
    unsigned pk = (unsigned)f2bf(v.x) | ((unsigned)f2bf(v.y) << 16);
    float nrm = v.x * v.x + v.y * v.y;
#pragma unroll
    for (int m = 1; m <= 32; m <<= 1) nrm += __shfl_xor(nrm, m, 64);
    if (isQ) {
        Qb[(size_t)r * 64 + lane] = pk;
        if (lane == 0) {
            qn[r] = nrm;
            qng[r] = make_float2(nrm, 2.f * cc * __builtin_amdgcn_rcpf(1.f - cc * nrm));
        }
        if (lane == 1) lws[r] = 0.f;                 // zero l accumulator (fallback path)
    } else {
        Kb[(size_t)r * 64 + lane] = pk;              // row-major, same as Q
        if (lane == 0) {
            kn[r] = nrm;
            kng[r] = make_float2(nrm, __builtin_amdgcn_rcpf(1.f - cc * nrm));
        }
    }
}

__global__ __launch_bounds__(256) void convv_kernel(const float* __restrict__ v, uint4* __restrict__ Vtb) {
    __shared__ unsigned short Vs[128 * 132];
    int b = blockIdx.x >> 4;
    int t = blockIdx.x & 15;
    int tid = threadIdx.x;
    const float* src = v + ((size_t)b * S_ + t * 128) * D_;
    int d4 = tid & 31, key0 = tid >> 5;
#pragma unroll
    for (int it = 0; it < 16; ++it) {
        int key = key0 + it * 8;
        float4 f = *(const float4*)(src + (size_t)key * D_ + d4 * 4);
        unsigned short* dst = &Vs[key * 132 + d4 * 4];
        dst[0] = f2bf(f.x); dst[1] = f2bf(f.y); dst[2] = f2bf(f.z); dst[3] = f2bf(f.w);
    }
    __syncthreads();
    uint4* tile = Vtb + (size_t)blockIdx.x * (128 * 16);   // [ks][d][quad] fragment-native
    int d = tid & 127;
    int cl = tid >> 7;
#pragma unroll
    for (int it = 0; it < 8; ++it) {
        int c = cl + it * 2;                          // k-octet 0..15
        int kb = c * 8;
        unsigned short e0 = Vs[(kb + 0) * 132 + d], e1 = Vs[(kb + 1) * 132 + d];
        unsigned short e2 = Vs[(kb + 2) * 132 + d], e3 = Vs[(kb + 3) * 132 + d];
        unsigned short e4 = Vs[(kb + 4) * 132 + d], e5 = Vs[(kb + 5) * 132 + d];
        unsigned short e6 = Vs[(kb + 6) * 132 + d], e7 = Vs[(kb + 7) * 132 + d];
        uint4 o;
        o.x = (unsigned)e0 | ((unsigned)e1 << 16);
        o.y = (unsigned)e2 | ((unsigned)e3 << 16);
        o.z = (unsigned)e4 | ((unsigned)e5 << 16);
        o.w = (unsigned)e6 | ((unsigned)e7 << 16);
        tile[(c >> 2) * 512 + d * 4 + (c & 3)] = o;   // ks*512 + d*4 + quad (uint4 units)
    }
}

// ===================== v9: barrier-free wave-autonomous loop (swapped QK) =====================
// 512 threads / 8 waves per block, 16 q-rows, grid 512 (2 blocks/CU). Wave wn owns 32-key
// chunks {ci*8+wn : ci=0..7} (all 2048 keys covered). Per chunk: S^T = mfma(K,Q) makes P
// lane-local (qrow=lm, keys quad*4+r); dist; P -> LDS (for W) AND -> PV A-fragment via 8
// quad-pair shuffles (no LDS round trip, NO barrier); private O accumulation over all 128 d.
// Loop has ZERO barriers -> waves drift, TLP hides MFMA/L2/trans latency.
// End: O 8-wave LDS-atomic reduction, l shfl+atomic, normalize + exp-map + hout, W tail.
//
// LDS map (74368 B): P_row @0 (16 x 4128), O_red @66048 (16x128 f32 = 8192),
//                    l_row @74240 (64), nsq_s @74304 (64).

__global__ __launch_bounds__(512, 4) void hattn9_kernel(
    const unsigned short* __restrict__ Qb, const unsigned short* __restrict__ Kb,
    const char* __restrict__ Vtb,
    const float2* __restrict__ qng, const float2* __restrict__ kng,
    const float* __restrict__ cp, const float* __restrict__ betap, const float* __restrict__ biasp,
    float* __restrict__ hout, float* __restrict__ wout) {

    __shared__ __align__(1024) char smem[74368];
    float* O_red = (float*)(smem + 66048);
    float* l_row = (float*)(smem + 74240);
    float* nsq_s = (float*)(smem + 74304);

    const int tid = threadIdx.x;
    const int lane = tid & 63, wn = tid >> 6;        // 8 waves
    const int lm = lane & 15, quad = lane >> 4;

    int xcd = blockIdx.x & 7;
    int b = xcd >> 1;
    int rb = (blockIdx.x >> 3) * 2 + (xcd & 1);      // 0..127
    int s0 = rb * 16;
    const size_t bS = (size_t)b * S_;

    const float beta = betap[0], bias = biasp[0];
    const float cc = cp[0];
    const float beta_pos = fmaxf(beta, 0.f) + log1pf(__expf(-fabsf(beta)));
    const float sqrt_c = sqrtf(cc);
    const float bneg = -beta_pos / sqrt_c;           // p = 2^(bneg*log2(w) + bias2)
    const float bias2 = -bias * 1.442695040888963f;
    const float onepe = 1.f + EPSF;

    const unsigned short* KbR = Kb + bS * D_;        // row-major keys
    const char* VtBase = Vtb + (size_t)b * 16 * 32768;

    // ---- prologue: zero O_red / l / nsq; per-thread q constants; Q B-frags ----
#pragma unroll
    for (int j = 0; j < 4; ++j) O_red[tid + j * 512] = 0.f;
    if (tid < 16) l_row[tid] = 0.f;
    else if (tid < 32) nsq_s[tid - 16] = 0.f;

    const float2 xq = qng[bS + s0 + lm];             // this thread's q-row constants

    short8 aq[4];
    {
        const unsigned short* qrow = Qb + (bS + s0 + lm) * D_;
#pragma unroll
        for (int ks = 0; ks < 4; ++ks)
            aq[ks] = *(const short8*)(qrow + ks * 32 + quad * 8);
    }
    __syncthreads();   // O_red/l/nsq zeroed

    f32x4 o0 = {0,0,0,0}, o1 = {0,0,0,0}, o2 = {0,0,0,0}, o3 = {0,0,0,0};
    f32x4 o4 = {0,0,0,0}, o5 = {0,0,0,0}, o6 = {0,0,0,0}, o7 = {0,0,0,0};
    float lacc = 0.f;

    const int srcA = lm + ((quad & 1) << 5);         // partner lanes for A-frag build
    const int srcB = srcA + 16;
    const bool hiT = quad >= 2;

    for (int ci = 0; ci < 8; ++ci) {
        const int chunk = ci * 8 + wn;               // 32-key chunk 0..63
        const int key0 = chunk * 32;

        // ---- K A-frags (rows = keys), two 16-key tiles ----
        const unsigned short* krow = KbR + (size_t)(key0 + lm) * D_;
        short8 kfA[4], kfB[4];
#pragma unroll
        for (int ks = 0; ks < 4; ++ks) {
            kfA[ks] = *(const short8*)(krow + ks * 32 + quad * 8);
            kfB[ks] = *(const short8*)(krow + 16 * D_ + ks * 32 + quad * 8);
        }

        // ---- key norms for this thread's 8 keys (broadcast loads) ----
        float2 ygA[4], ygB[4];
#pragma unroll
        for (int r = 0; r < 4; ++r) {
            ygA[r] = kng[bS + key0 + quad * 4 + r];
            ygB[r] = kng[bS + key0 + 16 + quad * 4 + r];
        }

        // ---- S^T = K Q^T : lane holds S[key=quad*4+r][qrow=lm] ----
        f32x4 sA = {0,0,0,0}, sB = {0,0,0,0};
#pragma unroll
        for (int ks = 0; ks < 4; ++ks) {
            sA = __builtin_amdgcn_mfma_f32_16x16x32_bf16(kfA[ks], aq[ks], sA, 0, 0, 0);
            sB = __builtin_amdgcn_mfma_f32_16x16x32_bf16(kfB[ks], aq[ks], sB, 0, 0, 0);
        }

        // ---- dist -> p (8 values, all for qrow=lm) ----
        unsigned short pb[8];
#pragma unroll
        for (int r = 0; r < 4; ++r) {
            float diff = fmaf(-2.f, sA[r], xq.x + ygA[r].x);
            float arg = fmaxf(fmaf(diff * ygA[r].y, xq.y, 1.f), onepe);
            float w = arg + sqrtf(fmaf(arg, arg, -1.f));
            float pv = __builtin_amdgcn_exp2f(fmaf(bneg, __builtin_amdgcn_logf(w), bias2));
            pb[r] = f2bf(pv);
            lacc += pv;

            float diff2 = fmaf(-2.f, sB[r], xq.x + ygB[r].x);
            float arg2 = fmaxf(fmaf(diff2 * ygB[r].y, xq.y, 1.f), onepe);
            float w2 = arg2 + sqrtf(fmaf(arg2, arg2, -1.f));
            float pv2 = __builtin_amdgcn_exp2f(fmaf(bneg, __builtin_amdgcn_logf(w2), bias2));
            pb[4 + r] = f2bf(pv2);
            lacc += pv2;
        }
        unsigned u0 = (unsigned)pb[0] | ((unsigned)pb[1] << 16);
        unsigned u1 = (unsigned)pb[2] | ((unsigned)pb[3] << 16);
        unsigned u2 = (unsigned)pb[4] | ((unsigned)pb[5] << 16);
        unsigned u3 = (unsigned)pb[6] | ((unsigned)pb[7] << 16);

        // ---- P -> LDS (for W tail; no reader until after loop) ----
        {
            char* pw = smem + lm * PRS + (key0 + quad * 4) * 2;
            *(uint2*)pw = make_uint2(u0, u1);
            *(uint2*)(pw + 32) = make_uint2(u2, u3);
        }

        // ---- build PV A-fragment in-register (quad-pair shuffles, no barrier) ----
        // dest (quad,lm) needs keys quad*8..+7: tile = quad>>1, src quads (quad&1)*2, +1
        unsigned a0, a1, a2, a3;
        {
            unsigned f0 = __shfl((int)u0, srcA), f1 = __shfl((int)u1, srcA);
            unsigned f2 = __shfl((int)u0, srcB), f3 = __shfl((int)u1, srcB);
            unsigned g0 = __shfl((int)u2, srcA), g1 = __shfl((int)u3, srcA);
            unsigned g2 = __shfl((int)u2, srcB), g3 = __shfl((int)u3, srcB);
            a0 = hiT ? g0 : f0; a1 = hiT ? g1 : f1;
            a2 = hiT ? g2 : f2; a3 = hiT ? g3 : f3;
        }
        union { unsigned u[4]; short8 s; } pa;
        pa.u[0] = a0; pa.u[1] = a1; pa.u[2] = a2; pa.u[3] = a3;

        // ---- O += P V over this 32-key chunk, all 128 d (8 d-tiles) ----
        const char* vb = VtBase + (size_t)(chunk >> 2) * 32768 + (chunk & 3) * 8192
                         + lm * 64 + quad * 16;
        {
            short8 vf;
            vf = *(const short8*)(vb + 0 * 1024);
            o0 = __builtin_amdgcn_mfma_f32_16x16x32_bf16(pa.s, vf, o0, 0, 0, 0);
            vf = *(const short8*)(vb + 1 * 1024);
            o1 = __builtin_amdgcn_mfma_f32_16x16x32_bf16(pa.s, vf, o1, 0, 0, 0);
            vf = *(const short8*)(vb + 2 * 1024);
            o2 = __builtin_amdgcn_mfma_f32_16x16x32_bf16(pa.s, vf, o2, 0, 0, 0);
            vf = *(const short8*)(vb + 3 * 1024);
            o3 = __builtin_amdgcn_mfma_f32_16x16x32_bf16(pa.s, vf, o3, 0, 0, 0);
            vf = *(const short8*)(vb + 4 * 1024);
            o4 = __builtin_amdgcn_mfma_f32_16x16x32_bf16(pa.s, vf, o4, 0, 0, 0);
            vf = *(const short8*)(vb + 5 * 1024);
            o5 = __builtin_amdgcn_mfma_f32_16x16x32_bf16(pa.s, vf, o5, 0, 0, 0);
            vf = *(const short8*)(vb + 6 * 1024);
            o6 = __builtin_amdgcn_mfma_f32_16x16x32_bf16(pa.s, vf, o6, 0, 0, 0);
            vf = *(const short8*)(vb + 7 * 1024);
            o7 = __builtin_amdgcn_mfma_f32_16x16x32_bf16(pa.s, vf, o7, 0, 0, 0);
        }
    }

    // ---- l: sum across quads (same qrow=lm), then one atomic per wave per row ----
    lacc += __shfl_xor(lacc, 16, 64);
    lacc += __shfl_xor(lacc, 32, 64);
    if (lane < 16) atomicAdd(&l_row[lm], lacc);

    // ---- O: 8-wave reduction into LDS (each (qrow,d) hit once per wave) ----
    // PV C-layout: qrow = quad*4+r, d = dt*16+lm
    {
        float* Obase = O_red + (quad * 4) * 128 + lm;
#pragma unroll
        for (int r = 0; r < 4; ++r) {
            atomicAdd(Obase + r * 128 + 0 * 16, o0[r]);
            atomicAdd(Obase + r * 128 + 1 * 16, o1[r]);
            atomicAdd(Obase + r * 128 + 2 * 16, o2[r]);
            atomicAdd(Obase + r * 128 + 3 * 16, o3[r]);
            atomicAdd(Obase + r * 128 + 4 * 16, o4[r]);
            atomicAdd(Obase + r * 128 + 5 * 16, o5[r]);
            atomicAdd(Obase + r * 128 + 6 * 16, o6[r]);
            atomicAdd(Obase + r * 128 + 7 * 16, o7[r]);
        }
    }
    __syncthreads();   // O_red, l_row complete

    // ---- normalize O, row-norm (wave-local reduce: each wave-j covers half a row) ----
    float xs[4];
#pragma unroll
    for (int j = 0; j < 4; ++j) {
        int idx = tid + j * 512;
        int row = idx >> 7;
        float x = O_red[idx] / l_row[row];
        xs[j] = x;
        float np = x * x;
#pragma unroll
        for (int m = 1; m <= 32; m <<= 1) np += __shfl_xor(np, m, 64);
        if (lane == 0) atomicAdd(&nsq_s[row], np);
    }
    __syncthreads();   // nsq complete

#pragma unroll
    for (int j = 0; j < 4; ++j) {
        int idx = tid + j * 512;
        int row = idx >> 7;
        float vn = fmaxf(sqrtf(nsq_s[row]), EPSF);
        float a = sqrt_c * vn;
        float th = 1.f - 2.f / (__expf(2.f * a) + 1.f);  // tanh(a)
        float sc = th / a;
        hout[(bS + s0 + row) * D_ + (idx & 127)] = xs[j] * sc;
    }

    // ---- P_lds -> normalized fp32 W, single coalesced write ----
    {
        float4* wdst = (float4*)(wout + (bS + s0) * (size_t)S_);
#pragma unroll
        for (int j = 0; j < 8; ++j) {
            int idx = tid + j * 512;                 // 4096 chunks = 16 rows x 256
            int row = idx >> 8;
            int ch = idx & 255;
            float lr = 1.f / l_row[row];
            uint4 u = *(const uint4*)(smem + row * PRS + ch * 16);
            float4 f0, f1;
            f0.x = __uint_as_float(u.x << 16) * lr;
            f0.y = __uint_as_float(u.x & 0xffff0000u) * lr;
            f0.z = __uint_as_float(u.y << 16) * lr;
            f0.w = __uint_as_float(u.y & 0xffff0000u) * lr;
            f1.x = __uint_as_float(u.z << 16) * lr;
            f1.y = __uint_as_float(u.z & 0xffff0000u) * lr;
            f1.z = __uint_as_float(u.w << 16) * lr;
            f1.w = __uint_as_float(u.w & 0xffff0000u) * lr;
            wdst[idx * 2] = f0;
            wdst[idx * 2 + 1] = f1;
        }
    }
}

// ===================== fallback path (LDS-staged; K row-major with XOR swizzle at stage) =====================

__global__ __launch_bounds__(512, 2) void hattn_kernel(
    const unsigned short* __restrict__ Qb, const unsigned short* __restrict__ Kb,
    const char* __restrict__ Vtb,
    const float* __restrict__ qn, const float* __restrict__ kn,
    const float* __restrict__ cp, const float* __restrict__ betap, const float* __restrict__ biasp,
    float* __restrict__ lws, float* __restrict__ houtg, float* __restrict__ woutg) {

    __shared__ __align__(1024) char smem[75136];
    char* KsB = smem;
    char* VtB = smem + 32768;
    char* PsB = smem + 65536;
    float* kn_s  = (float*)(smem + 74240);
    float* qn_s  = (float*)(smem + 74752);
    float* l_row = (float*)(smem + 74880);
    float* nsq_s = (float*)(smem + 75008);

    const int tid = threadIdx.x;
    const int lane = tid & 63, wave = tid >> 6;
    const int wm = wave & 1, wn = wave >> 1;
    const int lm = lane & 15, quad = lane >> 4;

    int xcd = blockIdx.x & 7;
    int b = xcd >> 1;
    int rb = (blockIdx.x >> 3) * 2 + (xcd & 1);
    int s0 = rb * 32;
    const size_t bS = (size_t)b * S_;

    const float cc = cp[0], beta = betap[0], bias = biasp[0];
    const float beta_pos = fmaxf(beta, 0.f) + log1pf(__expf(-fabsf(beta)));
    const float sqrt_c = sqrtf(cc);
    const float inv_sqrt_c = 1.f / sqrt_c;

    if (tid < 32) {
        qn_s[tid] = qn[bS + s0 + tid];
        l_row[tid] = 0.f;
        nsq_s[tid] = 0.f;
    }

    short8 aq[4];
    {
        const unsigned short* qrow = Qb + (bS + s0 + wm * 16 + lm) * D_;
#pragma unroll
        for (int ks = 0; ks < 4; ++ks)
            aq[ks] = *(const short8*)(qrow + ks * 32 + quad * 8);
    }

    f32x4 o0 = {0.f, 0.f, 0.f, 0.f}, o1 = {0.f, 0.f, 0.f, 0.f};

    const uint4* KbBase = (const uint4*)(Kb + bS * D_);
    const char* VtBase = Vtb + (size_t)b * 16 * 32768;

    for (int t = 0; t < S_ / BN; ++t) {
        int t0 = t * BN;
        __syncthreads();
        {
            const uint4* ksrc = KbBase + (size_t)t0 * 16;     // 128 rows x 16 uint4
            const uint4* vsrc = (const uint4*)(VtBase + (size_t)t * 32768);
            uint4* kd = (uint4*)KsB;
            uint4* vd = (uint4*)VtB;
#pragma unroll
            for (int i = 0; i < 4; ++i) {
                int idx = tid + i * 512;
                int row = idx >> 4, cch = idx & 15;
                kd[row * 16 + (cch ^ (row & 7))] = ksrc[idx];  // XOR swizzle at stage
                vd[idx] = vsrc[idx];
            }
            if (tid < BN) kn_s[tid] = kn[bS + t0 + tid];
        }
        __syncthreads();

        int n0 = wn * 32 + lm;
        f32x4 acc0 = {0.f, 0.f, 0.f, 0.f}, acc1 = {0.f, 0.f, 0.f, 0.f};
#pragma unroll
        for (int ks = 0; ks < 4; ++ks) {
            int c = ks * 4 + quad;
            short8 b0 = *(const short8*)(KsB + n0 * 256 + ((c ^ (n0 & 7)) * 16));
            int n1 = n0 + 16;
            short8 b1 = *(const short8*)(KsB + n1 * 256 + ((c ^ (n1 & 7)) * 16));
            acc0 = __builtin_amdgcn_mfma_f32_16x16x32_bf16(aq[ks], b0, acc0, 0, 0, 0);
            acc1 = __builtin_amdgcn_mfma_f32_16x16x32_bf16(aq[ks], b1, acc1, 0, 0, 0);
        }

        float lp[4];
#pragma unroll
        for (int r = 0; r < 4; ++r) {
            int row = wm * 16 + quad * 4 + r;
            float xn = qn_s[row];
            float fx = 1.f - cc * xn;
            float p0, p1;
#pragma unroll
            for (int nt = 0; nt < 2; ++nt) {
                int col = wn * 32 + nt * 16 + lm;
                float dot = (nt == 0) ? acc0[r] : acc1[r];
                float yn = kn_s[col];
                float diff = xn - 2.f * dot + yn;
                float den = fmaxf(fx * (1.f - cc * yn), EPSF);
                float arg = fmaf(2.f * cc * diff, __builtin_amdgcn_rcpf(den), 1.f);
                arg = fmaxf(arg, 1.f + EPSF);
                float dist = __logf(arg + sqrtf(arg * arg - 1.f)) * inv_sqrt_c;
                float p = __expf(fmaf(-beta_pos, dist, -bias));
                woutg[(bS + s0 + row) * S_ + t0 + col] = p;
                *(unsigned short*)(PsB + row * PSB + col * 2) = f2bf(p);
                if (nt == 0) p0 = p; else p1 = p;
            }
            lp[r] = p0 + p1;
        }
#pragma unroll
        for (int r = 0; r < 4; ++r) {
            float s = lp[r];
#pragma unroll
            for (int m = 1; m <= 8; m <<= 1) s += __shfl_xor(s, m, 64);
            if (lm == 0) atomicAdd(&l_row[wm * 16 + quad * 4 + r], s);
        }
        __syncthreads();

#pragma unroll
        for (int ks = 0; ks < 4; ++ks) {
            short8 ap = *(const short8*)(PsB + (wm * 16 + lm) * PSB + (ks * 32 + quad * 8) * 2);
            int d0 = wn * 32 + lm;
            short8 v0 = *(const short8*)(VtB + ks * 8192 + d0 * 64 + quad * 16);
            short8 v1 = *(const short8*)(VtB + ks * 8192 + (d0 + 16) * 64 + quad * 16);
            o0 = __builtin_amdgcn_mfma_f32_16x16x32_bf16(ap, v0, o0, 0, 0, 0);
            o1 = __builtin_amdgcn_mfma_f32_16x16x32_bf16(ap, v1, o1, 0, 0, 0);
        }
    }
    __syncthreads();

    float xs0[4], xs1[4];
#pragma unroll
    for (int r = 0; r < 4; ++r) {
        int row = wm * 16 + quad * 4 + r;
        float linv = __builtin_amdgcn_rcpf(l_row[row]);
        float x0 = o0[r] * linv, x1 = o1[r] * linv;
        xs0[r] = x0; xs1[r] = x1;
        float np = x0 * x0 + x1 * x1;
#pragma unroll
        for (int m = 1; m <= 8; m <<= 1) np += __shfl_xor(np, m, 64);
        if (lm == 0) atomicAdd(&nsq_s[row], np);
    }
    if (tid < 32) lws[bS + s0 + tid] = l_row[tid];
    __syncthreads();
#pragma unroll
    for (int r = 0; r < 4; ++r) {
        int row = wm * 16 + quad * 4 + r;
        float vn = fmaxf(sqrtf(nsq_s[row]), EPSF);
        float a = sqrt_c * vn;
        float th = 1.f - 2.f * __builtin_amdgcn_rcpf(__expf(2.f * a) + 1.f);
        float sc = th / a;
        houtg[(bS + s0 + row) * D_ + wn * 32 + lm] = xs0[r] * sc;
        houtg[(bS + s0 + row) * D_ + wn * 32 + 16 + lm] = xs1[r] * sc;
    }
}

__global__ __launch_bounds__(256) void wnorm_kernel(float* __restrict__ w,
                                                    const float* __restrict__ lws) {
    size_t idx = (size_t)blockIdx.x * 256 + threadIdx.x;
    int row = (int)(idx >> 9);
    float linv = 1.f / lws[row];
    float4* p = (float4*)w + idx;
    float4 v = *p;
    v.x *= linv; v.y *= linv; v.z *= linv; v.w *= linv;
    *p = v;
}

// ===================== launch =====================

extern "C" void kernel_launch(void* const* d_in, const int* in_sizes, int n_in,
                              void* d_out, int out_size, void* d_ws, size_t ws_size,
                              hipStream_t stream) {
    const float* q    = (const float*)d_in[0];
    const float* k    = (const float*)d_in[1];
    const float* v    = (const float*)d_in[2];
    const float* c    = (const float*)d_in[3];
    const float* beta = (const float*)d_in[4];
    const float* ab   = (const float*)d_in[5];

    float* out  = (float*)d_out;
    float* hout = out;                          // (B,S,D)
    float* wout = out + (size_t)B_ * S_ * D_;   // (B,S,S)

    float* qn  = (float*)d_ws;
    float* kn  = qn + B_ * S_;
    float* lws = kn + B_ * S_;
    char*  wsb = (char*)d_ws;
    const size_t QG_OFF = 98304;
    const size_t KG_OFF = QG_OFF + 65536;
    const size_t QB_OFF = KG_OFF + 65536;       // 229376
    const size_t KB_OFF = QB_OFF + 2097152;
    const size_t VT_OFF = KB_OFF + 2097152;
    const size_t NEED1  = VT_OFF + 2097152;

    float2*  qng = (float2*)(wsb + QG_OFF);
    float2*  kng = (float2*)(wsb + KG_OFF);
    unsigned* Qb = (unsigned*)(wsb + QB_OFF);
    unsigned* Kb = (unsigned*)(wsb + KB_OFF);
    uint4*   Vtb = (uint4*)(wsb + VT_OFF);

    if (ws_size >= NEED1) {
        convqk_kernel<<<4096, 256, 0, stream>>>(q, k, c, qn, kn, lws, qng, kng, Qb, Kb);
        convv_kernel<<<64, 256, 0, stream>>>(v, Vtb);
        hattn9_kernel<<<512, 512, 0, stream>>>((const unsigned short*)Qb, (const unsigned short*)Kb,
                                               (const char*)Vtb, qng, kng, c, beta, ab,
                                               hout, wout);
    } else {
        convqk_kernel<<<4096, 256, 0, stream>>>(q, k, c, qn, kn, lws, qng, kng, Qb, Kb);
        convv_kernel<<<64, 256, 0, stream>>>(v, Vtb);
        hattn_kernel<<<256, 512, 0, stream>>>((const unsigned short*)Qb, (const unsigned short*)Kb,
                                              (const char*)Vtb, qn, kn, c, beta, ab,
                                              lws, hout, wout);
        wnorm_kernel<<<(B_ * S_ * S_ / 4) / 256, 256, 0, stream>>>(wout, lws);
    }
}

// Round 9
// 154.562 us; speedup vs baseline: 1.2325x; 1.2325x over previous
//
#include <hip/hip_runtime.h>
#include <math.h>

#define B_ 4
#define S_ 2048
#define D_ 128
#define EPSF 1e-5f
#define BN 128
#define PSB 272     // fallback-path Ps row stride
#define SRS 272     // v10 stripe row stride (128 bf16 + 16B pad)

typedef __attribute__((ext_vector_type(8))) short short8;
typedef __attribute__((ext_vector_type(4))) float f32x4;

static __device__ __forceinline__ unsigned short f2bf(float f) {
    unsigned u = __float_as_uint(f);
    return (unsigned short)((u + 0x7fffu + ((u >> 16) & 1u)) >> 16);
}

// ===================== pre-pass kernels =====================
// Kb: row-major bf16 (fallback). KbA: A-fragment-native per 16-key tile:
//   byte = t16*4096 + ks*1024 + key_in_tile*64 + quad*16  -> wave A-frag load = 1024B contiguous.
// Vtb: B-fragment-native per 128-key tile: byte = kq*8192 + d*64 + quad*16.
// ws: [0,32K) qn, [32K,64K) kn, [64K,96K) lws, [96K,160K) qng, [160K,224K) kng,
//     [224K..) Qb(2M) Kb(2M) Vtb(2M) KbA(2M)

__global__ __launch_bounds__(256) void convqk_kernel(const float* __restrict__ q,
                                                     const float* __restrict__ k,
                                                     const float* __restrict__ cp,
                                                     float* __restrict__ qn, float* __restrict__ kn,
                                                     float* __restrict__ lws,
                                                     float2* __restrict__ qng, float2* __restrict__ kng,
                                                     unsigned* __restrict__ Qb, unsigned* __restrict__ Kb,
                                                     unsigned* __restrict__ KbA) {
    int row = blockIdx.x * 4 + (threadIdx.x >> 6);   // one wave per row, 16384 rows
    int lane = threadIdx.x & 63;
    const int NR = B_ * S_;
    const float cc = cp[0];
    bool isQ = row < NR;
    int r = isQ ? row : row - NR;
    float2 v = ((const float2*)(isQ ? q : k))[(size_t)r * 64 + lane];
    unsigned pk = (unsigned)f2bf(v.x) | ((unsigned)f2bf(v.y) << 16);
    float nrm = v.x * v.x + v.y * v.y;
#pragma unroll
    for (int m = 1; m <= 32; m <<= 1) nrm += __shfl_xor(nrm, m, 64);
    if (isQ) {
        Qb[(size_t)r * 64 + lane] = pk;
        if (lane == 0) {
            qn[r] = nrm;
            qng[r] = make_float2(nrm, 2.f * cc * __builtin_amdgcn_rcpf(1.f - cc * nrm));
        }
        if (lane == 1) lws[r] = 0.f;
    } else {
        Kb[(size_t)r * 64 + lane] = pk;              // row-major (fallback)
        int b = r >> 11, rloc = r & 2047;
        int t16 = rloc >> 4, kit = rloc & 15;
        KbA[(size_t)b * 131072 + t16 * 1024 + (lane >> 4) * 256 + kit * 16 +
            ((lane >> 2) & 3) * 4 + (lane & 3)] = pk;
        if (lane == 0) {
            kn[r] = nrm;
            kng[r] = make_float2(nrm, __builtin_amdgcn_rcpf(1.f - cc * nrm));
        }
    }
}

__global__ __launch_bounds__(256) void convv_kernel(const float* __restrict__ v, uint4* __restrict__ Vtb) {
    __shared__ unsigned short Vs[128 * 132];
    int b = blockIdx.x >> 4;
    int t = blockIdx.x & 15;
    int tid = threadIdx.x;
    const float* src = v + ((size_t)b * S_ + t * 128) * D_;
    int d4 = tid & 31, key0 = tid >> 5;
#pragma unroll
    for (int it = 0; it < 16; ++it) {
        int key = key0 + it * 8;
        float4 f = *(const float4*)(src + (size_t)key * D_ + d4 * 4);
        unsigned short* dst = &Vs[key * 132 + d4 * 4];
        dst[0] = f2bf(f.x); dst[1] = f2bf(f.y); dst[2] = f2bf(f.z); dst[3] = f2bf(f.w);
    }
    __syncthreads();
    uint4* tile = Vtb + (size_t)blockIdx.x * (128 * 16);   // [kq][d][quad] B-fragment-native
    int d = tid & 127;
    int cl = tid >> 7;
#pragma unroll
    for (int it = 0; it < 8; ++it) {
        int c = cl + it * 2;                          // k-octet 0..15
        int kb = c * 8;
        unsigned short e0 = Vs[(kb + 0) * 132 + d], e1 = Vs[(kb + 1) * 132 + d];
        unsigned short e2 = Vs[(kb + 2) * 132 + d], e3 = Vs[(kb + 3) * 132 + d];
        unsigned short e4 = Vs[(kb + 4) * 132 + d], e5 = Vs[(kb + 5) * 132 + d];
        unsigned short e6 = Vs[(kb + 6) * 132 + d], e7 = Vs[(kb + 7) * 132 + d];
        uint4 o;
        o.x = (unsigned)e0 | ((unsigned)e1 << 16);
        o.y = (unsigned)e2 | ((unsigned)e3 << 16);
        o.z = (unsigned)e4 | ((unsigned)e5 << 16);
        o.w = (unsigned)e6 | ((unsigned)e7 << 16);
        tile[(c >> 2) * 512 + d * 4 + (c & 3)] = o;
    }
}

// ===================== v10: two-pass, no P storage, no tail =====================
// 512 threads / 8 waves, 16 q-rows per block, grid 512. Swapped QK: S^T = mfma(K_A, Q_B),
// lane holds S[key=quad*4+r][qrow=lm]. K A-frags from coalesced A-native KbA (fixes v9).
// Pass 1 (barrier-free): QK + dist -> lacc registers -> l_row. Pass 2: recompute QK + dist,
// P normalized by 1/l (folded into exp2 bias), W written fp32 normalized per-iter (no tail),
// P -> bf16 -> tiny double-buffered LDS stripe -> PV (one f32x4 acc, O pre-normalized).
// One barrier/iter in pass 2 only. LDS = 8.9 KB.
//
// LDS map: stripe[2] @0/4352 (16 x 272B), l_row @8704 (16 f32), nsq_s @8768 (16 f32).

__global__ __launch_bounds__(512, 6) void hattn10_kernel(
    const unsigned short* __restrict__ Qb, const char* __restrict__ KbA,
    const char* __restrict__ Vtb,
    const float2* __restrict__ qng, const float2* __restrict__ kng,
    const float* __restrict__ cp, const float* __restrict__ betap, const float* __restrict__ biasp,
    float* __restrict__ hout, float* __restrict__ wout) {

    __shared__ __align__(1024) char smem[8832];
    float* l_row = (float*)(smem + 8704);
    float* nsq_s = (float*)(smem + 8768);

    const int tid = threadIdx.x;
    const int lane = tid & 63, wn = tid >> 6;        // 8 waves
    const int lm = lane & 15, quad = lane >> 4;

    int xcd = blockIdx.x & 7;
    int b = xcd >> 1;
    int rb = (blockIdx.x >> 3) * 2 + (xcd & 1);      // 0..127
    int s0 = rb * 16;
    const size_t bS = (size_t)b * S_;

    const float beta = betap[0], bias = biasp[0];
    const float cc = cp[0];
    const float beta_pos = fmaxf(beta, 0.f) + log1pf(__expf(-fabsf(beta)));
    const float sqrt_c = sqrtf(cc);
    const float bneg = -beta_pos / sqrt_c;           // p = 2^(bneg*log2(w) + bias2)
    const float bias2 = -bias * 1.442695040888963f;
    const float onepe = 1.f + EPSF;

    const char* KA = KbA + (size_t)b * 524288;
    const char* Vt = Vtb + (size_t)b * 524288;       // 16 tiles x 32 KB

    if (tid < 16) l_row[tid] = 0.f;
    else if (tid < 32) nsq_s[tid - 16] = 0.f;

    const float2 xq = qng[bS + s0 + lm];             // q-row constants (qrow = lm)

    short8 aq[4];                                    // Q B-frag: n=lm, k=quad*8+j
    {
        const unsigned short* qrow = Qb + (bS + s0 + lm) * D_;
#pragma unroll
        for (int ks = 0; ks < 4; ++ks)
            aq[ks] = *(const short8*)(qrow + ks * 32 + quad * 8);
    }
    __syncthreads();   // l_row/nsq_s zeroed

    // ================= pass 1: l only (barrier-free) =================
    float lacc = 0.f;
    for (int it = 0; it < 16; ++it) {
        int t16 = it * 8 + wn;                       // 16-key tile 0..127
        const char* ka = KA + t16 * 4096 + lm * 64 + quad * 16;
        short8 k0 = *(const short8*)(ka);
        short8 k1 = *(const short8*)(ka + 1024);
        short8 k2 = *(const short8*)(ka + 2048);
        short8 k3 = *(const short8*)(ka + 3072);
        const float4* yp = (const float4*)(kng + bS + t16 * 16 + quad * 4);
        float4 y01 = yp[0], y23 = yp[1];             // {yn,gy} x4 keys

        f32x4 s = {0.f, 0.f, 0.f, 0.f};
        s = __builtin_amdgcn_mfma_f32_16x16x32_bf16(k0, aq[0], s, 0, 0, 0);
        s = __builtin_amdgcn_mfma_f32_16x16x32_bf16(k1, aq[1], s, 0, 0, 0);
        s = __builtin_amdgcn_mfma_f32_16x16x32_bf16(k2, aq[2], s, 0, 0, 0);
        s = __builtin_amdgcn_mfma_f32_16x16x32_bf16(k3, aq[3], s, 0, 0, 0);

        float yn[4] = {y01.x, y01.z, y23.x, y23.z};
        float gy[4] = {y01.y, y01.w, y23.y, y23.w};
#pragma unroll
        for (int r = 0; r < 4; ++r) {
            float diff = fmaf(-2.f, s[r], xq.x + yn[r]);
            float arg = fmaxf(fmaf(diff * gy[r], xq.y, 1.f), onepe);
            float w = arg + sqrtf(fmaf(arg, arg, -1.f));
            lacc += __builtin_amdgcn_exp2f(fmaf(bneg, __builtin_amdgcn_logf(w), bias2));
        }
    }
    lacc += __shfl_xor(lacc, 16, 64);
    lacc += __shfl_xor(lacc, 32, 64);
    if (lane < 16) atomicAdd(&l_row[lm], lacc);
    __syncthreads();

    const float lrow = l_row[lm];
    const float linv = 1.f / lrow;
    const float bias3 = bias2 - __builtin_amdgcn_logf(lrow);   // fold 1/l into exp2

    // ================= pass 2: W + O (one barrier/iter) =================
    f32x4 o = {0.f, 0.f, 0.f, 0.f};
    int pbuf = 0;
    for (int it = 0; it < 16; ++it) {
        int t16 = it * 8 + wn;
        const char* ka = KA + t16 * 4096 + lm * 64 + quad * 16;
        short8 k0 = *(const short8*)(ka);
        short8 k1 = *(const short8*)(ka + 1024);
        short8 k2 = *(const short8*)(ka + 2048);
        short8 k3 = *(const short8*)(ka + 3072);
        const float4* yp = (const float4*)(kng + bS + t16 * 16 + quad * 4);
        float4 y01 = yp[0], y23 = yp[1];

        f32x4 s = {0.f, 0.f, 0.f, 0.f};
        s = __builtin_amdgcn_mfma_f32_16x16x32_bf16(k0, aq[0], s, 0, 0, 0);
        s = __builtin_amdgcn_mfma_f32_16x16x32_bf16(k1, aq[1], s, 0, 0, 0);
        s = __builtin_amdgcn_mfma_f32_16x16x32_bf16(k2, aq[2], s, 0, 0, 0);
        s = __builtin_amdgcn_mfma_f32_16x16x32_bf16(k3, aq[3], s, 0, 0, 0);

        float yn[4] = {y01.x, y01.z, y23.x, y23.z};
        float gy[4] = {y01.y, y01.w, y23.y, y23.w};
        float pv[4];
#pragma unroll
        for (int r = 0; r < 4; ++r) {
            float diff = fmaf(-2.f, s[r], xq.x + yn[r]);
            float arg = fmaxf(fmaf(diff * gy[r], xq.y, 1.f), onepe);
            float w = arg + sqrtf(fmaf(arg, arg, -1.f));
            pv[r] = __builtin_amdgcn_exp2f(fmaf(bneg, __builtin_amdgcn_logf(w), bias3));
        }

        // normalized fp32 W: row s0+lm, cols t16*16 + quad*4 .. +3 (16B store)
        {
            float4 wv = {pv[0], pv[1], pv[2], pv[3]};
            *(float4*)(wout + (bS + s0 + lm) * (size_t)S_ + t16 * 16 + quad * 4) = wv;
        }

        // normalized bf16 P -> stripe[pbuf][qrow=lm][col = wn*16 + quad*4 .. +3]
        {
            unsigned u0 = (unsigned)f2bf(pv[0]) | ((unsigned)f2bf(pv[1]) << 16);
            unsigned u1 = (unsigned)f2bf(pv[2]) | ((unsigned)f2bf(pv[3]) << 16);
            *(uint2*)(smem + pbuf * 4352 + lm * SRS + wn * 32 + quad * 8) = make_uint2(u0, u1);
        }
        __syncthreads();   // stripe complete (K/y loads long done; W store drains cheaply)

        // PV: A = stripe rows (qrow=lm), B = V frags; O[qrow=quad*4+r][d=wn*16+lm]
        {
            const char* sr = smem + pbuf * 4352 + lm * SRS;
            const char* vb = Vt + (size_t)it * 32768 + (wn * 16 + lm) * 64 + quad * 16;
#pragma unroll
            for (int kq = 0; kq < 4; ++kq) {
                short8 ap = *(const short8*)(sr + kq * 64 + quad * 16);
                short8 vf = *(const short8*)(vb + kq * 8192);
                o = __builtin_amdgcn_mfma_f32_16x16x32_bf16(ap, vf, o, 0, 0, 0);
            }
        }
        pbuf ^= 1;
    }

    // ---- row norms of (already normalized) O ----
#pragma unroll
    for (int r = 0; r < 4; ++r) {
        float np = o[r] * o[r];
#pragma unroll
        for (int m = 1; m <= 8; m <<= 1) np += __shfl_xor(np, m, 64);
        if (lm == 0) atomicAdd(&nsq_s[quad * 4 + r], np);
    }
    __syncthreads();   // nsq partial per wave... all 8 waves added their d-slices

#pragma unroll
    for (int r = 0; r < 4; ++r) {
        int row = quad * 4 + r;
        float vn = fmaxf(sqrtf(nsq_s[row]), EPSF);
        float a = sqrt_c * vn;
        float th = 1.f - 2.f / (__expf(2.f * a) + 1.f);  // tanh(a)
        float sc = th / a;
        hout[(bS + s0 + row) * D_ + wn * 16 + lm] = o[r] * sc;
    }
}

// ===================== fallback path (proven; row-major Kb + XOR swizzle) =====================

__global__ __launch_bounds__(512, 2) void hattn_kernel(
    const unsigned short* __restrict__ Qb, const unsigned short* __restrict__ Kb,
    const char* __restrict__ Vtb,
    const float* __restrict__ qn, const float* __restrict__ kn,
    const float* __restrict__ cp, const float* __restrict__ betap, const float* __restrict__ biasp,
    float* __restrict__ lws, float* __restrict__ houtg, float* __restrict__ woutg) {

    __shared__ __align__(1024) char smem[75136];
    char* KsB = smem;
    char* VtB = smem + 32768;
    char* PsB = smem + 65536;
    float* kn_s  = (float*)(smem + 74240);
    float* qn_s  = (float*)(smem + 74752);
    float* l_row = (float*)(smem + 74880);
    float* nsq_s = (float*)(smem + 75008);

    const int tid = threadIdx.x;
    const int lane = tid & 63, wave = tid >> 6;
    const int wm = wave & 1, wn = wave >> 1;
    const int lm = lane & 15, quad = lane >> 4;

    int xcd = blockIdx.x & 7;
    int b = xcd >> 1;
    int rb = (blockIdx.x >> 3) * 2 + (xcd & 1);
    int s0 = rb * 32;
    const size_t bS = (size_t)b * S_;

    const float cc = cp[0], beta = betap[0], bias = biasp[0];
    const float beta_pos = fmaxf(beta, 0.f) + log1pf(__expf(-fabsf(beta)));
    const float sqrt_c = sqrtf(cc);
    const float inv_sqrt_c = 1.f / sqrt_c;

    if (tid < 32) {
        qn_s[tid] = qn[bS + s0 + tid];
        l_row[tid] = 0.f;
        nsq_s[tid] = 0.f;
    }

    short8 aq[4];
    {
        const unsigned short* qrow = Qb + (bS + s0 + wm * 16 + lm) * D_;
#pragma unroll
        for (int ks = 0; ks < 4; ++ks)
            aq[ks] = *(const short8*)(qrow + ks * 32 + quad * 8);
    }

    f32x4 o0 = {0.f, 0.f, 0.f, 0.f}, o1 = {0.f, 0.f, 0.f, 0.f};

    const uint4* KbBase = (const uint4*)(Kb + bS * D_);
    const char* VtBase = Vtb + (size_t)b * 16 * 32768;

    for (int t = 0; t < S_ / BN; ++t) {
        int t0 = t * BN;
        __syncthreads();
        {
            const uint4* ksrc = KbBase + (size_t)t0 * 16;
            const uint4* vsrc = (const uint4*)(VtBase + (size_t)t * 32768);
            uint4* kd = (uint4*)KsB;
            uint4* vd = (uint4*)VtB;
#pragma unroll
            for (int i = 0; i < 4; ++i) {
                int idx = tid + i * 512;
                int row = idx >> 4, cch = idx & 15;
                kd[row * 16 + (cch ^ (row & 7))] = ksrc[idx];
                vd[idx] = vsrc[idx];
            }
            if (tid < BN) kn_s[tid] = kn[bS + t0 + tid];
        }
        __syncthreads();

        int n0 = wn * 32 + lm;
        f32x4 acc0 = {0.f, 0.f, 0.f, 0.f}, acc1 = {0.f, 0.f, 0.f, 0.f};
#pragma unroll
        for (int ks = 0; ks < 4; ++ks) {
            int c = ks * 4 + quad;
            short8 b0 = *(const short8*)(KsB + n0 * 256 + ((c ^ (n0 & 7)) * 16));
            int n1 = n0 + 16;
            short8 b1 = *(const short8*)(KsB + n1 * 256 + ((c ^ (n1 & 7)) * 16));
            acc0 = __builtin_amdgcn_mfma_f32_16x16x32_bf16(aq[ks], b0, acc0, 0, 0, 0);
            acc1 = __builtin_amdgcn_mfma_f32_16x16x32_bf16(aq[ks], b1, acc1, 0, 0, 0);
        }

        float lp[4];
#pragma unroll
        for (int r = 0; r < 4; ++r) {
            int row = wm * 16 + quad * 4 + r;
            float xn = qn_s[row];
            float fx = 1.f - cc * xn;
            float p0, p1;
#pragma unroll
            for (int nt = 0; nt < 2; ++nt) {
                int col = wn * 32 + nt * 16 + lm;
                float dot = (nt == 0) ? acc0[r] : acc1[r];
                float yn = kn_s[col];
                float diff = xn - 2.f * dot + yn;
                float den = fmaxf(fx * (1.f - cc * yn), EPSF);
                float arg = fmaf(2.f * cc * diff, __builtin_amdgcn_rcpf(den), 1.f);
                arg = fmaxf(arg, 1.f + EPSF);
                float dist = __logf(arg + sqrtf(arg * arg - 1.f)) * inv_sqrt_c;
                float p = __expf(fmaf(-beta_pos, dist, -bias));
                woutg[(bS + s0 + row) * S_ + t0 + col] = p;
                *(unsigned short*)(PsB + row * PSB + col * 2) = f2bf(p);
                if (nt == 0) p0 = p; else p1 = p;
            }
            lp[r] = p0 + p1;
        }
#pragma unroll
        for (int r = 0; r < 4; ++r) {
            float s = lp[r];
#pragma unroll
            for (int m = 1; m <= 8; m <<= 1) s += __shfl_xor(s, m, 64);
            if (lm == 0) atomicAdd(&l_row[wm * 16 + quad * 4 + r], s);
        }
        __syncthreads();

#pragma unroll
        for (int ks = 0; ks < 4; ++ks) {
            short8 ap = *(const short8*)(PsB + (wm * 16 + lm) * PSB + (ks * 32 + quad * 8) * 2);
            int d0 = wn * 32 + lm;
            short8 v0 = *(const short8*)(VtB + ks * 8192 + d0 * 64 + quad * 16);
            short8 v1 = *(const short8*)(VtB + ks * 8192 + (d0 + 16) * 64 + quad * 16);
            o0 = __builtin_amdgcn_mfma_f32_16x16x32_bf16(ap, v0, o0, 0, 0, 0);
            o1 = __builtin_amdgcn_mfma_f32_16x16x32_bf16(ap, v1, o1, 0, 0, 0);
        }
    }
    __syncthreads();

    float xs0[4], xs1[4];
#pragma unroll
    for (int r = 0; r < 4; ++r) {
        int row = wm * 16 + quad * 4 + r;
        float linv = __builtin_amdgcn_rcpf(l_row[row]);
        float x0 = o0[r] * linv, x1 = o1[r] * linv;
        xs0[r] = x0; xs1[r] = x1;
        float np = x0 * x0 + x1 * x1;
#pragma unroll
        for (int m = 1; m <= 8; m <<= 1) np += __shfl_xor(np, m, 64);
        if (lm == 0) atomicAdd(&nsq_s[row], np);
    }
    if (tid < 32) lws[bS + s0 + tid] = l_row[tid];
    __syncthreads();
#pragma unroll
    for (int r = 0; r < 4; ++r) {
        int row = wm * 16 + quad * 4 + r;
        float vn = fmaxf(sqrtf(nsq_s[row]), EPSF);
        float a = sqrt_c * vn;
        float th = 1.f - 2.f * __builtin_amdgcn_rcpf(__expf(2.f * a) + 1.f);
        float sc = th / a;
        houtg[(bS + s0 + row) * D_ + wn * 32 + lm] = xs0[r] * sc;
        houtg[(bS + s0 + row) * D_ + wn * 32 + 16 + lm] = xs1[r] * sc;
    }
}

__global__ __launch_bounds__(256) void wnorm_kernel(float* __restrict__ w,
                                                    const float* __restrict__ lws) {
    size_t idx = (size_t)blockIdx.x * 256 + threadIdx.x;
    int row = (int)(idx >> 9);
    float linv = 1.f / lws[row];
    float4* p = (float4*)w + idx;
    float4 v = *p;
    v.x *= linv; v.y *= linv; v.z *= linv; v.w *= linv;
    *p = v;
}

// ===================== launch =====================

extern "C" void kernel_launch(void* const* d_in, const int* in_sizes, int n_in,
                              void* d_out, int out_size, void* d_ws, size_t ws_size,
                              hipStream_t stream) {
    const float* q    = (const float*)d_in[0];
    const float* k    = (const float*)d_in[1];
    const float* v    = (const float*)d_in[2];
    const float* c    = (const float*)d_in[3];
    const float* beta = (const float*)d_in[4];
    const float* ab   = (const float*)d_in[5];

    float* out  = (float*)d_out;
    float* hout = out;                          // (B,S,D)
    float* wout = out + (size_t)B_ * S_ * D_;   // (B,S,S)

    float* qn  = (float*)d_ws;
    float* kn  = qn + B_ * S_;
    float* lws = kn + B_ * S_;
    char*  wsb = (char*)d_ws;
    const size_t QG_OFF = 98304;
    const size_t KG_OFF = QG_OFF + 65536;
    const size_t QB_OFF = KG_OFF + 65536;       // 229376
    const size_t KB_OFF = QB_OFF + 2097152;
    const size_t VT_OFF = KB_OFF + 2097152;
    const size_t KA_OFF = VT_OFF + 2097152;
    const size_t NEED1  = KA_OFF + 2097152;

    float2*  qng = (float2*)(wsb + QG_OFF);
    float2*  kng = (float2*)(wsb + KG_OFF);
    unsigned* Qb = (unsigned*)(wsb + QB_OFF);
    unsigned* Kb = (unsigned*)(wsb + KB_OFF);
    uint4*   Vtb = (uint4*)(wsb + VT_OFF);
    unsigned* KbA = (unsigned*)(wsb + KA_OFF);

    if (ws_size >= NEED1) {
        convqk_kernel<<<4096, 256, 0, stream>>>(q, k, c, qn, kn, lws, qng, kng, Qb, Kb, KbA);
        convv_kernel<<<64, 256, 0, stream>>>(v, Vtb);
        hattn10_kernel<<<512, 512, 0, stream>>>((const unsigned short*)Qb, (const char*)KbA,
                                                (const char*)Vtb, qng, kng, c, beta, ab,
                                                hout, wout);
    } else {
        convqk_kernel<<<4096, 256, 0, stream>>>(q, k, c, qn, kn, lws, qng, kng, Qb, Kb, KbA);
        convv_kernel<<<64, 256, 0, stream>>>(v, Vtb);
        hattn_kernel<<<256, 512, 0, stream>>>((const unsigned short*)Qb, (const unsigned short*)Kb,
                                              (const char*)Vtb, qn, kn, c, beta, ab,
                                              lws, hout, wout);
        wnorm_kernel<<<(B_ * S_ * S_ / 4) / 256, 256, 0, stream>>>(wout, lws);
    }
}